// Round 3
// baseline (273.869 us; speedup 1.0000x reference)
//
#include <hip/hip_runtime.h>
#include <math.h>

// Problem constants (match reference file).
#define BATCH 256
#define VOCAB 128000
#define HIST  2048
#define EPS_T 1e-5f

#define MASK_WORDS_ROW (VOCAB / 32)    // 4000 words = 16 KB per row

// --- kernel A: presence bitmask per row ---
#define ABLOCK 256

// --- kernel B: scan ---
#define SEGS 25
#define SEG_ELEMS (VOCAB / SEGS)       // 5120
#define SEG_VEC   (SEG_ELEMS / 4)      // 1280 float4s
#define SEG_WORDS (SEG_ELEMS / 32)     // 160 mask words per segment
#define BBLOCK 256
#define PAIRS (SEG_VEC / BBLOCK)       // exactly 5 float4s per thread, no tail
#define BWAVES (BBLOCK / 64)

__global__ __launch_bounds__(ABLOCK) void mask_kernel(
    const int* __restrict__ token_ids,       // [B, L]
    unsigned int* __restrict__ gmask)        // [B, MASK_WORDS_ROW]
{
    __shared__ unsigned int m[MASK_WORDS_ROW];
    const int b = blockIdx.x, tid = threadIdx.x;

    for (int i = tid; i < MASK_WORDS_ROW; i += ABLOCK) m[i] = 0u;
    __syncthreads();

    const int* rt = token_ids + (size_t)b * HIST;
    #pragma unroll
    for (int k = 0; k < HIST / ABLOCK; k++) {
        int t = rt[tid + k * ABLOCK];
        atomicOr(&m[t >> 5], 1u << (t & 31));
    }
    __syncthreads();

    unsigned int* gr = gmask + (size_t)b * MASK_WORDS_ROW;
    for (int i = tid; i < MASK_WORDS_ROW; i += ABLOCK) gr[i] = m[i];
}

__device__ __forceinline__ void upd(float s, int idx, float& best, int& besti) {
    if (s > best || (s == best && idx < besti)) { best = s; besti = idx; }
}

__global__ __launch_bounds__(BBLOCK) void scan_kernel(
    const float* __restrict__ logits,        // [B, V]
    const float* __restrict__ gumbel,        // [B, V]
    const unsigned int* __restrict__ gmask,  // [B, MASK_WORDS_ROW]
    const float* __restrict__ penalties,     // [B]
    const float* __restrict__ temps,         // [B]
    float* __restrict__ pvals,               // [SEGS][B]
    int*   __restrict__ pidxs)               // [SEGS][B]
{
    __shared__ float wval[BWAVES];
    __shared__ int   widx[BWAVES];

    const int blk = blockIdx.x;
    const int b   = blk / SEGS;
    const int seg = blk - b * SEGS;
    const int tid = threadIdx.x;

    const float pen    = penalties[b];
    const float temp   = temps[b];
    const bool  greedy = (temp < EPS_T);

    const float4*       lg = (const float4*)(logits + (size_t)b * VOCAB) + seg * SEG_VEC;
    const float4*       gm = (const float4*)(gumbel + (size_t)b * VOCAB) + seg * SEG_VEC;
    const unsigned int* mw = gmask + (size_t)b * MASK_WORDS_ROW + seg * SEG_WORDS;

    // one load burst: 5 logits float4 + 5 mask words (+5 gumbel float4 if sampled)
    float4 l[PAIRS];
    unsigned int w[PAIRS];
    #pragma unroll
    for (int k = 0; k < PAIRS; k++) l[k] = lg[tid + k * BBLOCK];
    #pragma unroll
    for (int k = 0; k < PAIRS; k++) w[k] = mw[k * (BBLOCK / 8) + (tid >> 3)];

    float best  = -INFINITY;
    int   besti = 0x7fffffff;
    const int sh = (tid * 4) & 31;            // uniform across k (stride 1024 elems)
    const int abs0 = seg * SEG_ELEMS;

    if (greedy) {
        #pragma unroll
        for (int k = 0; k < PAIRS; k++) {
            const int lv = tid + k * BBLOCK;
            float e[4] = {l[k].x, l[k].y, l[k].z, l[k].w};
            #pragma unroll
            for (int j = 0; j < 4; j++) {
                float present = (float)((w[k] >> (sh + j)) & 1u);
                float p = e[j] - pen * present;       // exact: present in {0,1}
                upd(p, abs0 + lv * 4 + j, best, besti);
            }
        }
    } else {
        float4 g[PAIRS];
        #pragma unroll
        for (int k = 0; k < PAIRS; k++) g[k] = gm[tid + k * BBLOCK];
        #pragma unroll
        for (int k = 0; k < PAIRS; k++) {
            const int lv = tid + k * BBLOCK;
            float e[4]  = {l[k].x, l[k].y, l[k].z, l[k].w};
            float gv[4] = {g[k].x, g[k].y, g[k].z, g[k].w};
            #pragma unroll
            for (int j = 0; j < 4; j++) {
                float present = (float)((w[k] >> (sh + j)) & 1u);
                float p = e[j] - pen * present;
                float s = p / temp + gv[j];           // reference op order, IEEE div
                upd(s, abs0 + lv * 4 + j, best, besti);
            }
        }
    }

    // wave argmax reduction (64 lanes), first-index tie-break
    #pragma unroll
    for (int off = 32; off > 0; off >>= 1) {
        float ov = __shfl_down(best, off, 64);
        int   oi = __shfl_down(besti, off, 64);
        if (ov > best || (ov == best && oi < besti)) { best = ov; besti = oi; }
    }
    const int wave = tid >> 6, lane = tid & 63;
    if (lane == 0) { wval[wave] = best; widx[wave] = besti; }
    __syncthreads();

    if (tid == 0) {
        #pragma unroll
        for (int wv = 1; wv < BWAVES; wv++) {
            if (wval[wv] > best || (wval[wv] == best && widx[wv] < besti)) {
                best = wval[wv]; besti = widx[wv];
            }
        }
        pvals[seg * BATCH + b] = best;    // [seg][row] -> coalesced reduce
        pidxs[seg * BATCH + b] = besti;
    }
}

__global__ void reduce_kernel(const float* __restrict__ pvals,
                              const int*   __restrict__ pidxs,
                              int*         __restrict__ out)
{
    const int b = threadIdx.x;            // 256 threads, one per row
    float best  = pvals[b];
    int   besti = pidxs[b];
    #pragma unroll
    for (int s = 1; s < SEGS; s++) {
        float v = pvals[s * BATCH + b];
        // strictly greater wins: ascending seg = ascending indices = numpy tie-break
        if (v > best) { best = v; besti = pidxs[s * BATCH + b]; }
    }
    out[b] = besti;
}

extern "C" void kernel_launch(void* const* d_in, const int* in_sizes, int n_in,
                              void* d_out, int out_size, void* d_ws, size_t ws_size,
                              hipStream_t stream) {
    const float* logits    = (const float*)d_in[0];
    const int*   token_ids = (const int*)d_in[1];
    const float* penalties = (const float*)d_in[2];
    const float* temps     = (const float*)d_in[3];
    const float* gumbel    = (const float*)d_in[4];
    int* out = (int*)d_out;

    unsigned int* gmask = (unsigned int*)d_ws;                       // 4,096,000 B
    float* pvals = (float*)((char*)d_ws + (size_t)BATCH * MASK_WORDS_ROW * 4);
    int*   pidxs = (int*)(pvals + SEGS * BATCH);

    mask_kernel<<<BATCH, ABLOCK, 0, stream>>>(token_ids, gmask);
    scan_kernel<<<BATCH * SEGS, BBLOCK, 0, stream>>>(logits, gumbel, gmask,
                                                     penalties, temps, pvals, pidxs);
    reduce_kernel<<<1, BATCH, 0, stream>>>(pvals, pidxs, out);
}

// Round 4
// 269.074 us; speedup vs baseline: 1.0178x; 1.0178x over previous
//
#include <hip/hip_runtime.h>
#include <math.h>

// Problem constants (match reference file).
#define BATCH 256
#define VOCAB 128000
#define HIST  2048
#define EPS_T 1e-5f

#define MASK_WORDS_ROW (VOCAB / 32)    // 4000 words = 16 KB per row

// --- kernel A: presence bitmask per row ---
#define ABLOCK 512

// --- kernel B: scan ---
#define SEGS 25
#define SEG_ELEMS (VOCAB / SEGS)       // 5120
#define SEG_VEC   (SEG_ELEMS / 4)      // 1280 float4s
#define SEG_WORDS (SEG_ELEMS / 32)     // 160 mask words per segment
#define BBLOCK 256
#define BWAVES (BBLOCK / 64)

__global__ __launch_bounds__(ABLOCK, 1) void mask_kernel(
    const int* __restrict__ token_ids,       // [B, L]
    unsigned int* __restrict__ gmask)        // [B, MASK_WORDS_ROW]
{
    __shared__ unsigned int m[MASK_WORDS_ROW];
    const int b = blockIdx.x, tid = threadIdx.x;

    for (int i = tid; i < MASK_WORDS_ROW; i += ABLOCK) m[i] = 0u;
    __syncthreads();

    // 2048 tokens / 512 threads = 4 each = one int4 load per thread
    const int4* rt = (const int4*)(token_ids + (size_t)b * HIST);
    int4 t = rt[tid];
    atomicOr(&m[t.x >> 5], 1u << (t.x & 31));
    atomicOr(&m[t.y >> 5], 1u << (t.y & 31));
    atomicOr(&m[t.z >> 5], 1u << (t.z & 31));
    atomicOr(&m[t.w >> 5], 1u << (t.w & 31));
    __syncthreads();

    // 4000 words / 512 threads: coalesced write-out
    unsigned int* gr = gmask + (size_t)b * MASK_WORDS_ROW;
    for (int i = tid; i < MASK_WORDS_ROW; i += ABLOCK) gr[i] = m[i];
}

__device__ __forceinline__ void upd(float s, int idx, float& best, int& besti) {
    if (s > best || (s == best && idx < besti)) { best = s; besti = idx; }
}

__device__ __forceinline__ void body4(float4 l, unsigned w, int sh, float pen,
                                      int idx0, float& best, int& besti) {
    float e[4] = {l.x, l.y, l.z, l.w};
    #pragma unroll
    for (int j = 0; j < 4; j++) {
        float present = (float)((w >> (sh + j)) & 1u);
        float p = e[j] - pen * present;           // exact: present in {0,1}
        upd(p, idx0 + j, best, besti);
    }
}

__device__ __forceinline__ void body4s(float4 l, float4 g, unsigned w, int sh,
                                       float pen, float temp,
                                       int idx0, float& best, int& besti) {
    float e[4]  = {l.x, l.y, l.z, l.w};
    float gv[4] = {g.x, g.y, g.z, g.w};
    #pragma unroll
    for (int j = 0; j < 4; j++) {
        float present = (float)((w >> (sh + j)) & 1u);
        float p = e[j] - pen * present;
        float s = p / temp + gv[j];               // reference op order, IEEE div
        upd(s, idx0 + j, best, besti);
    }
}

// min-waves=1: give the register allocator room to keep the whole load burst
// in flight (round-3's default heuristic capped VGPR=32 and serialized loads).
__global__ __launch_bounds__(BBLOCK, 1) void scan_kernel(
    const float* __restrict__ logits,        // [B, V]
    const float* __restrict__ gumbel,        // [B, V]
    const unsigned int* __restrict__ gmask,  // [B, MASK_WORDS_ROW]
    const float* __restrict__ penalties,     // [B]
    const float* __restrict__ temps,         // [B]
    float* __restrict__ pvals,               // [SEGS][B]
    int*   __restrict__ pidxs)               // [SEGS][B]
{
    __shared__ float wval[BWAVES];
    __shared__ int   widx[BWAVES];

    const int blk = blockIdx.x;
    const int b   = blk / SEGS;
    const int seg = blk - b * SEGS;
    const int tid = threadIdx.x;

    const float pen    = penalties[b];
    const float temp   = temps[b];
    const bool  greedy = (temp < EPS_T);

    const float4*       lg = (const float4*)(logits + (size_t)b * VOCAB) + seg * SEG_VEC;
    const float4*       gm = (const float4*)(gumbel + (size_t)b * VOCAB) + seg * SEG_VEC;
    const unsigned int* mw = gmask + (size_t)b * MASK_WORDS_ROW + seg * SEG_WORDS;

    // Explicit full burst: all loads named & issued before any consumption.
    float4 l0 = lg[tid];
    float4 l1 = lg[tid + 1 * BBLOCK];
    float4 l2 = lg[tid + 2 * BBLOCK];
    float4 l3 = lg[tid + 3 * BBLOCK];
    float4 l4 = lg[tid + 4 * BBLOCK];
    const int wbase = tid >> 3;                 // word idx stride 32 per k
    unsigned w0 = mw[wbase];
    unsigned w1 = mw[wbase + 32];
    unsigned w2 = mw[wbase + 64];
    unsigned w3 = mw[wbase + 96];
    unsigned w4 = mw[wbase + 128];

    float best  = -INFINITY;
    int   besti = 0x7fffffff;
    const int sh   = (tid * 4) & 31;            // uniform across k (stride 1024 elems)
    const int abs0 = seg * SEG_ELEMS + tid * 4;

    if (greedy) {
        body4(l0, w0, sh, pen, abs0 + 0 * BBLOCK * 4, best, besti);
        body4(l1, w1, sh, pen, abs0 + 1 * BBLOCK * 4, best, besti);
        body4(l2, w2, sh, pen, abs0 + 2 * BBLOCK * 4, best, besti);
        body4(l3, w3, sh, pen, abs0 + 3 * BBLOCK * 4, best, besti);
        body4(l4, w4, sh, pen, abs0 + 4 * BBLOCK * 4, best, besti);
    } else {
        float4 g0 = gm[tid];
        float4 g1 = gm[tid + 1 * BBLOCK];
        float4 g2 = gm[tid + 2 * BBLOCK];
        float4 g3 = gm[tid + 3 * BBLOCK];
        float4 g4 = gm[tid + 4 * BBLOCK];
        body4s(l0, g0, w0, sh, pen, temp, abs0 + 0 * BBLOCK * 4, best, besti);
        body4s(l1, g1, w1, sh, pen, temp, abs0 + 1 * BBLOCK * 4, best, besti);
        body4s(l2, g2, w2, sh, pen, temp, abs0 + 2 * BBLOCK * 4, best, besti);
        body4s(l3, g3, w3, sh, pen, temp, abs0 + 3 * BBLOCK * 4, best, besti);
        body4s(l4, g4, w4, sh, pen, temp, abs0 + 4 * BBLOCK * 4, best, besti);
    }

    // wave argmax reduction (64 lanes), first-index tie-break
    #pragma unroll
    for (int off = 32; off > 0; off >>= 1) {
        float ov = __shfl_down(best, off, 64);
        int   oi = __shfl_down(besti, off, 64);
        if (ov > best || (ov == best && oi < besti)) { best = ov; besti = oi; }
    }
    const int wave = tid >> 6, lane = tid & 63;
    if (lane == 0) { wval[wave] = best; widx[wave] = besti; }
    __syncthreads();

    if (tid == 0) {
        #pragma unroll
        for (int wv = 1; wv < BWAVES; wv++) {
            if (wval[wv] > best || (wval[wv] == best && widx[wv] < besti)) {
                best = wval[wv]; besti = widx[wv];
            }
        }
        pvals[seg * BATCH + b] = best;    // [seg][row] -> coalesced reduce
        pidxs[seg * BATCH + b] = besti;
    }
}

__global__ void reduce_kernel(const float* __restrict__ pvals,
                              const int*   __restrict__ pidxs,
                              int*         __restrict__ out)
{
    const int b = threadIdx.x;            // 256 threads, one per row
    float best  = pvals[b];
    int   besti = pidxs[b];
    #pragma unroll
    for (int s = 1; s < SEGS; s++) {
        float v = pvals[s * BATCH + b];
        // strictly greater wins: ascending seg = ascending indices = numpy tie-break
        if (v > best) { best = v; besti = pidxs[s * BATCH + b]; }
    }
    out[b] = besti;
}

extern "C" void kernel_launch(void* const* d_in, const int* in_sizes, int n_in,
                              void* d_out, int out_size, void* d_ws, size_t ws_size,
                              hipStream_t stream) {
    const float* logits    = (const float*)d_in[0];
    const int*   token_ids = (const int*)d_in[1];
    const float* penalties = (const float*)d_in[2];
    const float* temps     = (const float*)d_in[3];
    const float* gumbel    = (const float*)d_in[4];
    int* out = (int*)d_out;

    unsigned int* gmask = (unsigned int*)d_ws;                       // 4,096,000 B
    float* pvals = (float*)((char*)d_ws + (size_t)BATCH * MASK_WORDS_ROW * 4);
    int*   pidxs = (int*)(pvals + SEGS * BATCH);

    mask_kernel<<<BATCH, ABLOCK, 0, stream>>>(token_ids, gmask);
    scan_kernel<<<BATCH * SEGS, BBLOCK, 0, stream>>>(logits, gumbel, gmask,
                                                     penalties, temps, pvals, pidxs);
    reduce_kernel<<<1, BATCH, 0, stream>>>(pvals, pidxs, out);
}

// Round 5
// 266.693 us; speedup vs baseline: 1.0269x; 1.0089x over previous
//
#include <hip/hip_runtime.h>
#include <math.h>

// Problem constants (match reference file).
#define BATCH 256
#define VOCAB 128000
#define HIST  2048
#define EPS_T 1e-5f

#define MASK_WORDS_ROW (VOCAB / 32)    // 4000 words = 16 KB per row

// --- kernel A: presence bitmask per row ---
#define ABLOCK 512

// --- kernel B: scan ---
#define SEGS 25
#define SEG_ELEMS (VOCAB / SEGS)       // 5120
#define SEG_VEC   (SEG_ELEMS / 4)      // 1280 float4s
#define SEG_WORDS (SEG_ELEMS / 32)     // 160 mask words per segment
#define BBLOCK 256
#define BWAVES (BBLOCK / 64)

__global__ __launch_bounds__(ABLOCK, 1) void mask_kernel(
    const int* __restrict__ token_ids,       // [B, L]
    unsigned int* __restrict__ gmask)        // [B, MASK_WORDS_ROW]
{
    __shared__ unsigned int m[MASK_WORDS_ROW];
    const int b = blockIdx.x, tid = threadIdx.x;

    for (int i = tid; i < MASK_WORDS_ROW; i += ABLOCK) m[i] = 0u;
    __syncthreads();

    // 2048 tokens / 512 threads = 4 each = one int4 load per thread
    const int4* rt = (const int4*)(token_ids + (size_t)b * HIST);
    int4 t = rt[tid];
    atomicOr(&m[t.x >> 5], 1u << (t.x & 31));
    atomicOr(&m[t.y >> 5], 1u << (t.y & 31));
    atomicOr(&m[t.z >> 5], 1u << (t.z & 31));
    atomicOr(&m[t.w >> 5], 1u << (t.w & 31));
    __syncthreads();

    unsigned int* gr = gmask + (size_t)b * MASK_WORDS_ROW;
    for (int i = tid; i < MASK_WORDS_ROW; i += ABLOCK) gr[i] = m[i];
}

__device__ __forceinline__ void upd(float s, int idx, float& best, int& besti) {
    if (s > best || (s == best && idx < besti)) { best = s; besti = idx; }
}

__device__ __forceinline__ void body4(float4 l, unsigned w, int sh, float pen,
                                      int idx0, float& best, int& besti) {
    float e[4] = {l.x, l.y, l.z, l.w};
    #pragma unroll
    for (int j = 0; j < 4; j++) {
        float present = (float)((w >> (sh + j)) & 1u);
        float p = e[j] - pen * present;           // exact: present in {0,1}
        upd(p, idx0 + j, best, besti);
    }
}

__device__ __forceinline__ void body4s(float4 l, float4 g, unsigned w, int sh,
                                       float pen, float temp,
                                       int idx0, float& best, int& besti) {
    float e[4]  = {l.x, l.y, l.z, l.w};
    float gv[4] = {g.x, g.y, g.z, g.w};
    #pragma unroll
    for (int j = 0; j < 4; j++) {
        float present = (float)((w >> (sh + j)) & 1u);
        float p = e[j] - pen * present;
        float s = p / temp + gv[j];               // reference op order, IEEE div
        upd(s, idx0 + j, best, besti);
    }
}

// launch_bounds(256,1): VGPR budget up to 512.
// sched_barrier(0) pins the load burst: scheduler may not interleave the
// loads with their uses (round-4 showed it re-serializes otherwise, VGPR=32).
__global__ __launch_bounds__(BBLOCK, 1) void scan_kernel(
    const float* __restrict__ logits,        // [B, V]
    const float* __restrict__ gumbel,        // [B, V]
    const unsigned int* __restrict__ gmask,  // [B, MASK_WORDS_ROW]
    const float* __restrict__ penalties,     // [B]
    const float* __restrict__ temps,         // [B]
    float* __restrict__ pvals,               // [SEGS][B]
    int*   __restrict__ pidxs)               // [SEGS][B]
{
    __shared__ float wval[BWAVES];
    __shared__ int   widx[BWAVES];

    const int blk = blockIdx.x;
    const int b   = blk / SEGS;
    const int seg = blk - b * SEGS;
    const int tid = threadIdx.x;

    const float pen    = penalties[b];
    const float temp   = temps[b];
    const bool  greedy = (temp < EPS_T);

    const float4*       lg = (const float4*)(logits + (size_t)b * VOCAB) + seg * SEG_VEC;
    const float4*       gm = (const float4*)(gumbel + (size_t)b * VOCAB) + seg * SEG_VEC;
    const unsigned int* mw = gmask + (size_t)b * MASK_WORDS_ROW + seg * SEG_WORDS;

    float best  = -INFINITY;
    int   besti = 0x7fffffff;
    const int sh    = (tid * 4) & 31;           // uniform across k (stride 1024 elems)
    const int abs0  = seg * SEG_ELEMS + tid * 4;
    const int wbase = tid >> 3;                 // mask word idx, stride 32 per k

    if (greedy) {
        // full burst: 5 float4 + 5 words issued before ANY consumption
        float4 l0 = lg[tid];
        float4 l1 = lg[tid + 1 * BBLOCK];
        float4 l2 = lg[tid + 2 * BBLOCK];
        float4 l3 = lg[tid + 3 * BBLOCK];
        float4 l4 = lg[tid + 4 * BBLOCK];
        unsigned w0 = mw[wbase];
        unsigned w1 = mw[wbase + 32];
        unsigned w2 = mw[wbase + 64];
        unsigned w3 = mw[wbase + 96];
        unsigned w4 = mw[wbase + 128];
        __builtin_amdgcn_sched_barrier(0);      // nothing crosses: loads stay hoisted
        body4(l0, w0, sh, pen, abs0 + 0 * BBLOCK * 4, best, besti);
        body4(l1, w1, sh, pen, abs0 + 1 * BBLOCK * 4, best, besti);
        body4(l2, w2, sh, pen, abs0 + 2 * BBLOCK * 4, best, besti);
        body4(l3, w3, sh, pen, abs0 + 3 * BBLOCK * 4, best, besti);
        body4(l4, w4, sh, pen, abs0 + 4 * BBLOCK * 4, best, besti);
    } else {
        float4 l0 = lg[tid];
        float4 l1 = lg[tid + 1 * BBLOCK];
        float4 l2 = lg[tid + 2 * BBLOCK];
        float4 l3 = lg[tid + 3 * BBLOCK];
        float4 l4 = lg[tid + 4 * BBLOCK];
        float4 g0 = gm[tid];
        float4 g1 = gm[tid + 1 * BBLOCK];
        float4 g2 = gm[tid + 2 * BBLOCK];
        float4 g3 = gm[tid + 3 * BBLOCK];
        float4 g4 = gm[tid + 4 * BBLOCK];
        unsigned w0 = mw[wbase];
        unsigned w1 = mw[wbase + 32];
        unsigned w2 = mw[wbase + 64];
        unsigned w3 = mw[wbase + 96];
        unsigned w4 = mw[wbase + 128];
        __builtin_amdgcn_sched_barrier(0);      // nothing crosses: loads stay hoisted
        body4s(l0, g0, w0, sh, pen, temp, abs0 + 0 * BBLOCK * 4, best, besti);
        body4s(l1, g1, w1, sh, pen, temp, abs0 + 1 * BBLOCK * 4, best, besti);
        body4s(l2, g2, w2, sh, pen, temp, abs0 + 2 * BBLOCK * 4, best, besti);
        body4s(l3, g3, w3, sh, pen, temp, abs0 + 3 * BBLOCK * 4, best, besti);
        body4s(l4, g4, w4, sh, pen, temp, abs0 + 4 * BBLOCK * 4, best, besti);
    }

    // wave argmax reduction (64 lanes), first-index tie-break
    #pragma unroll
    for (int off = 32; off > 0; off >>= 1) {
        float ov = __shfl_down(best, off, 64);
        int   oi = __shfl_down(besti, off, 64);
        if (ov > best || (ov == best && oi < besti)) { best = ov; besti = oi; }
    }
    const int wave = tid >> 6, lane = tid & 63;
    if (lane == 0) { wval[wave] = best; widx[wave] = besti; }
    __syncthreads();

    if (tid == 0) {
        #pragma unroll
        for (int wv = 1; wv < BWAVES; wv++) {
            if (wval[wv] > best || (wval[wv] == best && widx[wv] < besti)) {
                best = wval[wv]; besti = widx[wv];
            }
        }
        pvals[seg * BATCH + b] = best;    // [seg][row] -> coalesced reduce
        pidxs[seg * BATCH + b] = besti;
    }
}

__global__ void reduce_kernel(const float* __restrict__ pvals,
                              const int*   __restrict__ pidxs,
                              int*         __restrict__ out)
{
    const int b = threadIdx.x;            // 256 threads, one per row
    float best  = pvals[b];
    int   besti = pidxs[b];
    #pragma unroll
    for (int s = 1; s < SEGS; s++) {
        float v = pvals[s * BATCH + b];
        // strictly greater wins: ascending seg = ascending indices = numpy tie-break
        if (v > best) { best = v; besti = pidxs[s * BATCH + b]; }
    }
    out[b] = besti;
}

extern "C" void kernel_launch(void* const* d_in, const int* in_sizes, int n_in,
                              void* d_out, int out_size, void* d_ws, size_t ws_size,
                              hipStream_t stream) {
    const float* logits    = (const float*)d_in[0];
    const int*   token_ids = (const int*)d_in[1];
    const float* penalties = (const float*)d_in[2];
    const float* temps     = (const float*)d_in[3];
    const float* gumbel    = (const float*)d_in[4];
    int* out = (int*)d_out;

    unsigned int* gmask = (unsigned int*)d_ws;                       // 4,096,000 B
    float* pvals = (float*)((char*)d_ws + (size_t)BATCH * MASK_WORDS_ROW * 4);
    int*   pidxs = (int*)(pvals + SEGS * BATCH);

    mask_kernel<<<BATCH, ABLOCK, 0, stream>>>(token_ids, gmask);
    scan_kernel<<<BATCH * SEGS, BBLOCK, 0, stream>>>(logits, gumbel, gmask,
                                                     penalties, temps, pvals, pidxs);
    reduce_kernel<<<1, BATCH, 0, stream>>>(pvals, pidxs, out);
}